// Round 15
// baseline (397.563 us; speedup 1.0000x reference)
//
#include <hip/hip_runtime.h>
#include <hip/hip_bf16.h>
#include <math.h>

#define HD 1024
#define NCLS 10001

typedef short s16x8 __attribute__((ext_vector_type(8)));
typedef unsigned short u16x8 __attribute__((ext_vector_type(8)));
typedef unsigned short u16x4 __attribute__((ext_vector_type(4)));
typedef float f32x4 __attribute__((ext_vector_type(4)));
#define MFMA16(a_, b_, c_) __builtin_amdgcn_mfma_f32_16x16x32_bf16((a_), (b_), (c_), 0, 0, 0)

__device__ __forceinline__ float sigf(float x){ return 1.f/(1.f+__expf(-x)); }
__device__ __forceinline__ float tanhfast(float x){
  x = fminf(fmaxf(x,-10.f),10.f);
  float e2 = __expf(2.f*x);
  return (e2-1.f)/(e2+1.f);
}
__device__ __forceinline__ unsigned short f2bf(float f){
  unsigned int u = __float_as_uint(f);
  u += 0x7FFF + ((u >> 16) & 1);          // round-to-nearest-even
  return (unsigned short)(u >> 16);
}
__device__ __forceinline__ float bf2f(unsigned short u){
  return __uint_as_float(((unsigned)u) << 16);
}
__device__ __forceinline__ u16x8 pack8(float4 a, float4 b){
  u16x8 r;
  r[0]=f2bf(a.x); r[1]=f2bf(a.y); r[2]=f2bf(a.z); r[3]=f2bf(a.w);
  r[4]=f2bf(b.x); r[5]=f2bf(b.y); r[6]=f2bf(b.z); r[7]=f2bf(b.w);
  return r;
}

// ---------------- merged fp32->bf16 conversion — block-uniform arrays, forced 8-load MLP ----------------
// block ranges: [0,3072) Wih, [3072,5120) Whh, [5120,5184) ann, [5184,5312) Watt, [5312,5568) Wpre
__global__ __launch_bounds__(256) void k_cvtall(
    const float* __restrict__ Wih, const float* __restrict__ Whh,
    const float* __restrict__ ann, const float* __restrict__ Watt, const float* __restrict__ Wpre,
    unsigned short* __restrict__ Wbih, unsigned short* __restrict__ Wbhh,
    unsigned short* __restrict__ Annb, unsigned short* __restrict__ Wattb,
    unsigned short* __restrict__ Bpre, unsigned short* __restrict__ Wpcb)
{
  const int b = blockIdx.x;
  if (b >= 5312) {     // W_pre split path (per-lane column split)
    unsigned base = (unsigned)(b-5312)*8192u;
    #pragma unroll
    for (int it=0; it<4; ++it) {
      unsigned idx = base + ((unsigned)it*256u + threadIdx.x)*8u;
      const float* sp = Wpre + idx;
      unsigned row = idx >> 11, c = idx & 2047;
      unsigned short* dp = (c < 1024) ? (Bpre + (size_t)row*1536 + c) : (Wpcb + (size_t)row*1024 + (c-1024));
      float4 a = *(const float4*)sp, bb = *(const float4*)(sp+4);
      *(u16x8*)dp = pack8(a,bb);
    }
    return;
  }
  const float* src; unsigned short* dst;
  if (b < 3072)      { unsigned o=(unsigned)b*8192u;        src=Wih+o;  dst=Wbih+o; }
  else if (b < 5120) { unsigned o=(unsigned)(b-3072)*8192u; src=Whh+o;  dst=Wbhh+o; }
  else if (b < 5184) { unsigned o=(unsigned)(b-5120)*8192u; src=ann+o;  dst=Annb+o; }
  else               { unsigned o=(unsigned)(b-5184)*8192u; src=Watt+o; dst=Wattb+o; }

  const unsigned t8 = threadIdx.x*8u;
  float4 a0 = *(const float4*)(src +        t8), b0 = *(const float4*)(src +        t8 + 4);
  float4 a1 = *(const float4*)(src + 2048 + t8), b1 = *(const float4*)(src + 2048 + t8 + 4);
  float4 a2 = *(const float4*)(src + 4096 + t8), b2 = *(const float4*)(src + 4096 + t8 + 4);
  float4 a3 = *(const float4*)(src + 6144 + t8), b3 = *(const float4*)(src + 6144 + t8 + 4);
  // pin all 8 loads live here -> compiler cannot sink them between stores (MLP depth 8)
  asm volatile("" :: "v"(a0.x), "v"(b0.x), "v"(a1.x), "v"(b1.x),
                     "v"(a2.x), "v"(b2.x), "v"(a3.x), "v"(b3.x));
  *(u16x8*)(dst +        t8) = pack8(a0,b0);
  *(u16x8*)(dst + 2048 + t8) = pack8(a1,b1);
  *(u16x8*)(dst + 4096 + t8) = pack8(a2,b2);
  *(u16x8*)(dst + 6144 + t8) = pack8(a3,b3);
}

// ---------------- emb halves of all LSTM inputs (one-shot; tree topology is static) ----------------
__global__ __launch_bounds__(64) void k_emb(const float* __restrict__ emb, const int* __restrict__ values,
                                            unsigned short* __restrict__ Xb){
  int i = blockIdx.x + 1;                  // 1..255
  int lev, s;
  if (i < 5)       { lev=1; s=1; }
  else if (i < 21) { lev=2; s=5; }
  else if (i < 85) { lev=3; s=21; }
  else             { lev=4; s=85; }
  int p = (i-1)>>2, o = i - s;
  unsigned short* xr = Xb + ((size_t)(lev-1)*4*48 + (size_t)(o&3)*48 + (o>>2)) * 2560;
  const float* er = emb + (size_t)values[p]*512;
  int c = threadIdx.x*8;
  float4 a = *(const float4*)(er+c), b = *(const float4*)(er+c+4);
  *(u16x8*)(xr+c) = pack8(a,b);
}

// ---------------- root: C, XH h, and h into level-1 child slots ----------------
__global__ __launch_bounds__(256) void k_root(const float* __restrict__ rH, const float* __restrict__ rC,
                                              float* __restrict__ Cb, unsigned short* __restrict__ XH,
                                              unsigned short* __restrict__ Xb1){
  int u = threadIdx.x*4;
  float4 h = *(const float4*)(rH+u);
  float4 c = *(const float4*)(rC+u);
  *(float4*)(Cb+u) = c;
  u16x4 r; r[0]=f2bf(h.x); r[1]=f2bf(h.y); r[2]=f2bf(h.z); r[3]=f2bf(h.w);
  *(u16x4*)(XH+u) = r;
  #pragma unroll
  for (int k=0;k<4;++k)
    *(u16x4*)(Xb1 + (size_t)k*48*2560 + 1536 + u) = r;
}

// ---------------- full-K bf16 GEMM (AHV / ANWT prep) ----------------
template<int MT>
__global__ __launch_bounds__(256) void k_gemm_fb(
    const unsigned short* __restrict__ A, int astride,
    const unsigned short* __restrict__ B, int K,
    const float* __restrict__ bias,
    unsigned short* __restrict__ Cb16,
    int ostride, int coff, int N, int M)
{
  const int mb0 = blockIdx.y * (MT*16);
  const int wv = threadIdx.x >> 6, lane = threadIdx.x & 63;
  const int col = (blockIdx.x*4 + wv)*16 + (lane & 15);
  const int colc = min(col, N-1);
  const int khalf = (lane >> 4) * 8;

  f32x4 acc[MT];
  #pragma unroll
  for (int m = 0; m < MT; ++m) acc[m] = (f32x4){0.f,0.f,0.f,0.f};
  int arow[MT];
  #pragma unroll
  for (int m = 0; m < MT; ++m) arow[m] = min(mb0 + m*16 + (lane & 15), M-1);

  #pragma unroll 4
  for (int kk = 0; kk < K; kk += 32) {
    int kb = kk + khalf;
    s16x8 bfv = *(const s16x8*)(B + (size_t)colc*K + kb);
    #pragma unroll
    for (int m = 0; m < MT; ++m) {
      s16x8 af = *(const s16x8*)(A + (size_t)arow[m]*astride + kb);
      acc[m] = MFMA16(af, bfv, acc[m]);
    }
  }

  const int r0 = (lane >> 4) * 4;
  #pragma unroll
  for (int m = 0; m < MT; ++m) {
    #pragma unroll
    for (int q = 0; q < 4; ++q) {
      int row = mb0 + m*16 + r0 + q;
      if (row < M && col < N) {
        float v = acc[m][q] + (bias ? bias[col] : 0.f);
        Cb16[(size_t)row*ostride + col + coff] = f2bf(v);
      }
    }
  }
}

// ---------------- W_out GEMM: fp32 B staged+converted to LDS (row-clamped, no OOB) ----------------
__global__ __launch_bounds__(256) void k_wout(
    const unsigned short* __restrict__ A,      // Etb [256][1024]
    const float* __restrict__ B,               // W_out fp32 [10001][1024]
    const float* __restrict__ bias,
    unsigned short* __restrict__ Lgb)
{
  __shared__ unsigned short bs[16*1032];
  const int c0 = blockIdx.x*16;
  const int tid = threadIdx.x;
  #pragma unroll
  for (int it = 0; it < 8; ++it) {
    int e = it*2048 + tid*8;
    int row = e >> 10, ck = e & 1023;
    int rr = min(c0 + row, NCLS-1);
    const float* sp = B + (size_t)rr*1024 + ck;
    float4 a = *(const float4*)sp, b = *(const float4*)(sp+4);
    *(u16x8*)(bs + row*1032 + ck) = pack8(a,b);
  }
  __syncthreads();

  const int wv = tid >> 6, lane = tid & 63;
  const int col16 = lane & 15;
  const int khalf = (lane >> 4) * 8;
  const int mb0 = wv * 64;
  const int col = c0 + col16;

  f32x4 acc[4];
  #pragma unroll
  for (int m=0;m<4;++m) acc[m] = (f32x4){0.f,0.f,0.f,0.f};
  int arow[4];
  #pragma unroll
  for (int m=0;m<4;++m) arow[m] = mb0 + m*16 + col16;

  #pragma unroll 8
  for (int kk = 0; kk < 1024; kk += 32) {
    int kb = kk + khalf;
    s16x8 bfv = *(const s16x8*)(bs + col16*1032 + kb);
    #pragma unroll
    for (int m=0;m<4;++m) {
      s16x8 af = *(const s16x8*)(A + (size_t)arow[m]*1024 + kb);
      acc[m] = MFMA16(af, bfv, acc[m]);
    }
  }

  if (col < NCLS) {
    const int r0 = (lane >> 4) * 4;
    float bv = bias[col];
    #pragma unroll
    for (int m=0;m<4;++m) {
      #pragma unroll
      for (int q=0;q<4;++q) {
        int row = mb0 + m*16 + r0 + q;
        Lgb[(size_t)row*NCLS + col] = f2bf(acc[m][q] + bv);
      }
    }
  }
}

// ---------------- split-K + slot-batched bf16 GEMM (LSTM), B split B1|B2 ----------------
template<int MT, int KITER>
__global__ __launch_bounds__(256) void k_gemm_skzb2(
    const unsigned short* __restrict__ A, int astride,
    const unsigned short* __restrict__ B1, int K1,
    const unsigned short* __restrict__ B2, int K2,
    float* __restrict__ P, int N, int Mbase, int Mpad,
    int aZ, int b1Z, int b2Z, int KS)
{
  const int z = blockIdx.z;
  const int M = (Mbase - z + 3) >> 2;
  const unsigned short* Az = A + (size_t)z*aZ;
  const unsigned short* B1z = B1 + (size_t)z*b1Z;
  const unsigned short* B2z = B2 + (size_t)z*b2Z;
  const int ks = blockIdx.y;
  const int k0 = ks * (KITER*32);
  const int wv = threadIdx.x >> 6, lane = threadIdx.x & 63;
  const int col = (blockIdx.x*4 + wv)*16 + (lane & 15);
  const int colc = min(col, N-1);
  const int khalf = (lane >> 4) * 8;

  f32x4 acc[MT];
  #pragma unroll
  for (int m = 0; m < MT; ++m) acc[m] = (f32x4){0.f,0.f,0.f,0.f};
  int arow[MT];
  #pragma unroll
  for (int m = 0; m < MT; ++m) arow[m] = min(m*16 + (lane & 15), M-1);

  #pragma unroll 8
  for (int kk = 0; kk < KITER*32; kk += 32) {
    int kb = k0 + kk + khalf;
    const unsigned short* bp = (kb < K1) ? (B1z + (size_t)colc*K1 + kb)
                                         : (B2z + (size_t)colc*K2 + (kb - K1));
    s16x8 bfv = *(const s16x8*)bp;
    #pragma unroll
    for (int m = 0; m < MT; ++m) {
      s16x8 af = *(const s16x8*)(Az + (size_t)arow[m]*astride + kb);
      acc[m] = MFMA16(af, bfv, acc[m]);
    }
  }

  const int r0 = (lane >> 4) * 4;
  #pragma unroll
  for (int m = 0; m < MT; ++m) {
    #pragma unroll
    for (int q = 0; q < 4; ++q) {
      int row = m*16 + r0 + q;
      if (row < M && col < N)
        P[(((size_t)z*KS + ks)*Mpad + row)*N + col] = acc[m][q];
    }
  }
}

// ---------------- small split-K bf16 GEMM (chunk 128): P[ks][M][N] ----------------
template<int MT>
__global__ __launch_bounds__(256) void k_gemm_skb(
    const unsigned short* __restrict__ A, int astride,
    const unsigned short* __restrict__ B, int K,
    float* __restrict__ P, int N, int M)
{
  const int ks = blockIdx.y;
  const int k0 = ks * 128;
  const int wv = threadIdx.x >> 6, lane = threadIdx.x & 63;
  const int col = (blockIdx.x*4 + wv)*16 + (lane & 15);
  const int colc = min(col, N-1);
  const int khalf = (lane >> 4) * 8;

  f32x4 acc[MT];
  #pragma unroll
  for (int m = 0; m < MT; ++m) acc[m] = (f32x4){0.f,0.f,0.f,0.f};
  int arow[MT];
  #pragma unroll
  for (int m = 0; m < MT; ++m) arow[m] = min(m*16 + (lane & 15), M-1);

  #pragma unroll
  for (int kk = 0; kk < 128; kk += 32) {
    int kb = k0 + kk + khalf;
    s16x8 bfv = *(const s16x8*)(B + (size_t)colc*K + kb);
    #pragma unroll
    for (int m = 0; m < MT; ++m) {
      s16x8 af = *(const s16x8*)(A + (size_t)arow[m]*astride + kb);
      acc[m] = MFMA16(af, bfv, acc[m]);
    }
  }

  const int r0 = (lane >> 4) * 4;
  #pragma unroll
  for (int m = 0; m < MT; ++m) {
    #pragma unroll
    for (int q = 0; q < 4; ++q) {
      int row = m*16 + r0 + q;
      if (row < M && col < N)
        P[((size_t)ks*M + row)*N + col] = acc[m][q];
    }
  }
}

// ---------------- fused split-K sum + softmax over 512 logits -> bf16 probs into XH[.][1024:1536] ----------------
__global__ __launch_bounds__(256) void k_soft(const float* __restrict__ P, int KS, int M,
                                              unsigned short* __restrict__ dst)  // XH + s*1536 + 1024
{
  __shared__ float sm[512];
  __shared__ float red[8];
  const int m = blockIdx.x;
  const int tid = threadIdx.x, wv = tid>>6, ln = tid&63;
  for (int l = tid; l < 512; l += 256) {
    float s = 0.f;
    for (int ks = 0; ks < KS; ++ks) s += P[((size_t)ks*M + m)*512 + l];
    sm[l] = s;
  }
  __syncthreads();
  float mx = -1e30f;
  for (int l=tid; l<512; l+=256) mx = fmaxf(mx, sm[l]);
  #pragma unroll
  for (int o=32;o;o>>=1) mx = fmaxf(mx, __shfl_xor(mx,o,64));
  if (ln==0) red[wv]=mx;
  __syncthreads();
  mx = fmaxf(fmaxf(red[0],red[1]),fmaxf(red[2],red[3]));
  float se = 0.f;
  for (int l=tid; l<512; l+=256){ float ev=__expf(sm[l]-mx); sm[l]=ev; se+=ev; }
  __syncthreads();
  #pragma unroll
  for (int o=32;o;o>>=1) se += __shfl_xor(se,o,64);
  if (ln==0) red[wv]=se;
  __syncthreads();
  float invS = 1.f/(red[0]+red[1]+red[2]+red[3]);
  for (int l=tid; l<512; l+=256) dst[(size_t)m*1536 + l] = f2bf(sm[l]*invS);
}

// ---------------- et reduction: block per row; tanh; write Etb + scatter to children Xb ----------------
__global__ __launch_bounds__(256) void k_red4(const float* __restrict__ P, int KS, int M,
                                              const float* __restrict__ bias,
                                              unsigned short* __restrict__ Etb, int s,
                                              int snext, unsigned short* __restrict__ XbNext)
{
  const int row = blockIdx.x;
  const int col = threadIdx.x*4;
  float4 sum = *(const float4*)(bias + col);
  for (int ks = 0; ks < KS; ++ks) {
    float4 p = *(const float4*)(P + ((size_t)ks*M + row)*1024 + col);
    sum.x += p.x; sum.y += p.y; sum.z += p.z; sum.w += p.w;
  }
  u16x4 r;
  r[0]=f2bf(tanhfast(sum.x)); r[1]=f2bf(tanhfast(sum.y));
  r[2]=f2bf(tanhfast(sum.z)); r[3]=f2bf(tanhfast(sum.w));
  *(u16x4*)(Etb + (size_t)(s+row)*1024 + col) = r;
  if (XbNext) {
    int cbase = 4*(s+row) + 1;
    #pragma unroll
    for (int k=0;k<4;++k) {
      int cn = cbase + k;
      if (cn < 256) {
        int o = cn - snext;
        *(u16x4*)(XbNext + ((size_t)(o&3)*48 + (o>>2))*2560 + 512 + col) = r;
      }
    }
  }
}

// ---------------- LSTM epilogue: gates -> h,c; scatter h to children Xb ----------------
__global__ __launch_bounds__(256) void k_epi(const float* __restrict__ P,
                                             const float* __restrict__ b_ih, const float* __restrict__ b_hh,
                                             float* __restrict__ Cb, unsigned short* __restrict__ XH,
                                             int s, int snext, unsigned short* __restrict__ XbNext){
  int i = s + blockIdx.x;
  int slot = (i - s) & 3, j = (i - s) >> 2;
  int p = (i - 1) >> 2;
  const float* bi = b_ih + (size_t)slot*4096;
  const float* bh = b_hh + (size_t)slot*4096;
  const int u = threadIdx.x*4;

  float4 ig, fg, gg, og;
  {
    float4 a, b;
    a = *(const float4*)(bi+u);      b = *(const float4*)(bh+u);      ig = make_float4(a.x+b.x,a.y+b.y,a.z+b.z,a.w+b.w);
    a = *(const float4*)(bi+1024+u); b = *(const float4*)(bh+1024+u); fg = make_float4(a.x+b.x,a.y+b.y,a.z+b.z,a.w+b.w);
    a = *(const float4*)(bi+2048+u); b = *(const float4*)(bh+2048+u); gg = make_float4(a.x+b.x,a.y+b.y,a.z+b.z,a.w+b.w);
    a = *(const float4*)(bi+3072+u); b = *(const float4*)(bh+3072+u); og = make_float4(a.x+b.x,a.y+b.y,a.z+b.z,a.w+b.w);
  }
  #pragma unroll
  for (int ks = 0; ks < 5; ++ks) {
    const float* g = P + (((size_t)slot*5 + ks)*48 + j)*4096;
    float4 a;
    a = *(const float4*)(g+u);      ig.x+=a.x; ig.y+=a.y; ig.z+=a.z; ig.w+=a.w;
    a = *(const float4*)(g+1024+u); fg.x+=a.x; fg.y+=a.y; fg.z+=a.z; fg.w+=a.w;
    a = *(const float4*)(g+2048+u); gg.x+=a.x; gg.y+=a.y; gg.z+=a.z; gg.w+=a.w;
    a = *(const float4*)(g+3072+u); og.x+=a.x; og.y+=a.y; og.z+=a.z; og.w+=a.w;
  }
  float4 cp = *(const float4*)(Cb + (size_t)p*1024 + u);
  float4 cc, hh;
  cc.x = sigf(fg.x)*cp.x + sigf(ig.x)*tanhfast(gg.x); hh.x = sigf(og.x)*tanhfast(cc.x);
  cc.y = sigf(fg.y)*cp.y + sigf(ig.y)*tanhfast(gg.y); hh.y = sigf(og.y)*tanhfast(cc.y);
  cc.z = sigf(fg.z)*cp.z + sigf(ig.z)*tanhfast(gg.z); hh.z = sigf(og.z)*tanhfast(cc.z);
  cc.w = sigf(fg.w)*cp.w + sigf(ig.w)*tanhfast(gg.w); hh.w = sigf(og.w)*tanhfast(cc.w);
  *(float4*)(Cb + (size_t)i*1024 + u) = cc;
  u16x4 r; r[0]=f2bf(hh.x); r[1]=f2bf(hh.y); r[2]=f2bf(hh.z); r[3]=f2bf(hh.w);
  *(u16x4*)(XH + (size_t)i*1536 + u) = r;
  if (XbNext) {
    int cbase = 4*i + 1;
    #pragma unroll
    for (int k=0;k<4;++k) {
      int cn = cbase + k;
      if (cn < 256) {
        int o = cn - snext;
        *(u16x4*)(XbNext + ((size_t)(o&3)*48 + (o>>2))*2560 + 1536 + u) = r;
      }
    }
  }
}

// ---------------- loss per node (bf16 logits, register-cached single read) ----------------
__global__ __launch_bounds__(256) void k_loss(const unsigned short* __restrict__ Lgb,
                                              const int* __restrict__ values,
                                              float* __restrict__ Nl)
{
  __shared__ float red[8];
  const int node = blockIdx.x;
  const int tid = threadIdx.x, wv = tid>>6, ln = tid&63;
  const unsigned short* lg = Lgb + (size_t)node*NCLS;

  u16x8 v0 = *(const u16x8*)(lg + 0*2048 + tid*8);
  u16x8 v1 = *(const u16x8*)(lg + 1*2048 + tid*8);
  u16x8 v2 = *(const u16x8*)(lg + 2*2048 + tid*8);
  u16x8 v3 = *(const u16x8*)(lg + 3*2048 + tid*8);
  u16x8 v4;
  {
    int e = 8192 + tid*8;
    #pragma unroll
    for (int k=0;k<8;++k) v4[k] = (e+k < NCLS) ? lg[e+k] : (unsigned short)0xFF80;
  }

  float m = -1e30f;
  #pragma unroll
  for (int k=0;k<8;++k){
    m = fmaxf(m, bf2f(v0[k])); m = fmaxf(m, bf2f(v1[k]));
    m = fmaxf(m, bf2f(v2[k])); m = fmaxf(m, bf2f(v3[k]));
    m = fmaxf(m, bf2f(v4[k]));
  }
  #pragma unroll
  for (int o=32;o;o>>=1) m = fmaxf(m, __shfl_xor(m,o,64));
  if (ln==0) red[wv]=m;
  __syncthreads();
  m = fmaxf(fmaxf(red[0],red[1]),fmaxf(red[2],red[3]));
  __syncthreads();

  float s = 0.f;
  #pragma unroll
  for (int k=0;k<8;++k){
    s += __expf(bf2f(v0[k])-m); s += __expf(bf2f(v1[k])-m);
    s += __expf(bf2f(v2[k])-m); s += __expf(bf2f(v3[k])-m);
    s += __expf(bf2f(v4[k])-m);
  }
  #pragma unroll
  for (int o=32;o;o>>=1) s += __shfl_xor(s,o,64);
  if (ln==0) red[wv]=s;
  __syncthreads();
  s = red[0]+red[1]+red[2]+red[3];
  __syncthreads();
  float invs = 1.f/s;

  float q = 0.f;
  #pragma unroll
  for (int k=0;k<8;++k){
    q += __expf(__expf(bf2f(v0[k])-m)*invs);
    q += __expf(__expf(bf2f(v1[k])-m)*invs);
    q += __expf(__expf(bf2f(v2[k])-m)*invs);
    q += __expf(__expf(bf2f(v3[k])-m)*invs);
    if (8192 + tid*8 + k < NCLS) q += __expf(__expf(bf2f(v4[k])-m)*invs);
  }
  #pragma unroll
  for (int o=32;o;o>>=1) q += __shfl_xor(q,o,64);
  if (ln==0) red[wv]=q;
  __syncthreads();
  if (tid==0) {
    float qq = red[0]+red[1]+red[2]+red[3];
    int v = values[node];
    float pv = __expf(bf2f(lg[v])-m)*invs;
    float nl = __logf(qq) - pv;
    if (v == NCLS-1) nl *= 0.2f;
    Nl[node] = nl;
  }
}

__global__ __launch_bounds__(256) void k_final(const float* __restrict__ Nl, float* __restrict__ out){
  __shared__ float red[8];
  int tid = threadIdx.x, wv = tid>>6, ln = tid&63;
  float s = Nl[tid];
  #pragma unroll
  for (int o=32;o;o>>=1) s += __shfl_xor(s,o,64);
  if (ln==0) red[wv]=s;
  __syncthreads();
  if (tid==0) out[0] = red[0]+red[1]+red[2]+red[3];
}

static inline void gemm_skb(hipStream_t st, int MT, const unsigned short* A, int astride,
                            const unsigned short* B, int K, float* P, int N, int M)
{
  dim3 grid(N/64, K/128);
  #define SKCASE(MTv) k_gemm_skb<MTv><<<grid, 256, 0, st>>>(A,astride,B,K,P,N,M)
  switch(MT){
    case 1:  SKCASE(1);  break;
    case 4:  SKCASE(4);  break;
    case 11: SKCASE(11); break;
    default: SKCASE(16); break;
  }
  #undef SKCASE
}

extern "C" void kernel_launch(void* const* d_in, const int* in_sizes, int n_in,
                              void* d_out, int out_size, void* d_ws, size_t ws_size,
                              hipStream_t stream)
{
  const float* rootH = (const float*)d_in[0];
  const float* rootC = (const float*)d_in[1];
  const float* ann   = (const float*)d_in[2];
  const int*   values= (const int*)d_in[3];
  const float* emb   = (const float*)d_in[6];
  const float* W_ih  = (const float*)d_in[7];
  const float* W_hh  = (const float*)d_in[8];
  const float* b_ih  = (const float*)d_in[9];
  const float* b_hh  = (const float*)d_in[10];
  const float* W_att = (const float*)d_in[11];
  const float* b_att = (const float*)d_in[12];
  const float* W_pre = (const float*)d_in[13];
  const float* b_pre = (const float*)d_in[14];
  const float* W_out = (const float*)d_in[15];
  const float* b_out = (const float*)d_in[16];

  float* ws = (float*)d_ws;
  float* Cb  = ws; ws += 256*1024;              // fp32 c
  float* Nl  = ws; ws += 256;
  float* PB  = ws; ws += 4*5*48*4096;           // shared split-K partials
  unsigned short* Wbih  = (unsigned short*)ws;  // bf16 [4][4096][1536]
  unsigned short* Wbhh  = Wbih  + (size_t)4*4096*1536;   // bf16 [4][4096][1024]
  unsigned short* Wattb = Wbhh  + (size_t)4*4096*1024;   // bf16 [1024][1024]
  unsigned short* Bpre  = Wattb + 1024*1024;    // bf16 [1024][1536] = [W_pre_h | ANWT]
  unsigned short* Wpcb  = Bpre  + 1024*1536;    // bf16 [1024][1024] W_pre ctx half
  unsigned short* AHVb  = Wpcb  + 1024*1024;    // bf16 [512][1024]
  unsigned short* Annb  = AHVb  + 512*1024;     // bf16 [512][1024]
  unsigned short* XH    = Annb  + 512*1024;     // bf16 [256][1536] = [h | probs]
  unsigned short* Etb   = XH    + 256*1536;     // bf16 [256][1024]
  unsigned short* Xb    = Etb   + 256*1024;     // bf16 [4 levels][4][48][2560]
  unsigned short* Lgb   = Xb    + (size_t)4*4*48*2560;   // bf16 [256][10001] logits

  // ---- one-time prep ----
  k_cvtall<<<5568, 256, 0, stream>>>(W_ih, W_hh, ann, W_att, W_pre,
                                     Wbih, Wbhh, Annb, Wattb, Bpre, Wpcb);
  k_emb   <<<255,  64,  0, stream>>>(emb, values, Xb);
  // AHV = ann @ W_att^T + b_att  (bf16 out)
  k_gemm_fb<4><<<dim3(16,8), 256, 0, stream>>>(Annb, 1024, Wattb, 1024, b_att, AHVb, 1024, 0, 1024, 512);
  // ANWT[out][l] = W_pre_ctx[out]·ann[l] -> Bpre[out][1024:1536]
  k_gemm_fb<4><<<dim3(8,16), 256, 0, stream>>>(Wpcb, 1024, Annb, 1024, nullptr, Bpre, 1536, 1024, 512, 1024);
  k_root<<<1, 256, 0, stream>>>(rootH, rootC, Cb, XH, Xb);

  const int LS[6] = {0,1,5,21,85,256};
  for (int lev=0; lev<5; ++lev){
    int s=LS[lev], e=LS[lev+1], n=e-s;
    unsigned short* XbL = Xb + (size_t)(lev-1)*4*48*2560;       // this level's LSTM input (lev>=1)
    unsigned short* XbN = (lev<4) ? (Xb + (size_t)lev*4*48*2560) : nullptr;  // children's
    int snext = (lev<4) ? LS[lev+1] : 0;
    if (lev>0){
      if (lev==4)
        k_gemm_skzb2<3,16><<<dim3(64,5,4),256,0,stream>>>(XbL, 2560, Wbih, 1536, Wbhh, 1024, PB,
            4096, n, 48, 48*2560, 4096*1536, 4096*1024, 5);
      else
        k_gemm_skzb2<1,16><<<dim3(64,5,4),256,0,stream>>>(XbL, 2560, Wbih, 1536, Wbhh, 1024, PB,
            4096, n, 48, 48*2560, 4096*1536, 4096*1024, 5);
      k_epi<<<n,256,0,stream>>>(PB, b_ih, b_hh, Cb, XH, s, snext, XbN);
    }
    int mtn = (n+15)/16;
    // attention logits [n x 512] = h · AHV^T (split-K MFMA) + fused softmax -> probs in XH
    gemm_skb(stream, mtn, XH + (size_t)s*1536, 1536, AHVb, 1024, PB, 512, n);
    k_soft<<<n,256,0,stream>>>(PB, 8, n, XH + (size_t)s*1536 + 1024);
    // et = tanh([h|probs] · Bpre^T + b_pre): split-K + per-row reduce (+ scatter to children Xb)
    gemm_skb(stream, mtn, XH + (size_t)s*1536, 1536, Bpre, 1536, PB, 1024, n);
    k_red4<<<n,256,0,stream>>>(PB, 12, n, b_pre, Etb, s, snext, XbN);
  }

  // W_out logits: fp32 B staged->LDS with convert, bf16 output
  k_wout<<<626, 256, 0, stream>>>(Etb, W_out, b_out, Lgb);
  k_loss <<<256,256,0,stream>>>(Lgb, values, Nl);
  k_final<<<1,  256,0,stream>>>(Nl, (float*)d_out);
}

// Round 17
// 395.522 us; speedup vs baseline: 1.0052x; 1.0052x over previous
//
#include <hip/hip_runtime.h>
#include <hip/hip_bf16.h>
#include <math.h>

#define HD 1024
#define NCLS 10001

typedef short s16x8 __attribute__((ext_vector_type(8)));
typedef unsigned short u16x8 __attribute__((ext_vector_type(8)));
typedef unsigned short u16x4 __attribute__((ext_vector_type(4)));
typedef float f32x4 __attribute__((ext_vector_type(4)));
#define MFMA16(a_, b_, c_) __builtin_amdgcn_mfma_f32_16x16x32_bf16((a_), (b_), (c_), 0, 0, 0)

__device__ __forceinline__ float sigf(float x){ return 1.f/(1.f+__expf(-x)); }
__device__ __forceinline__ float tanhfast(float x){
  x = fminf(fmaxf(x,-10.f),10.f);
  float e2 = __expf(2.f*x);
  return (e2-1.f)/(e2+1.f);
}
__device__ __forceinline__ unsigned short f2bf(float f){
  unsigned int u = __float_as_uint(f);
  u += 0x7FFF + ((u >> 16) & 1);          // round-to-nearest-even
  return (unsigned short)(u >> 16);
}
__device__ __forceinline__ float bf2f(unsigned short u){
  return __uint_as_float(((unsigned)u) << 16);
}
__device__ __forceinline__ u16x8 pack8(float4 a, float4 b){
  u16x8 r;
  r[0]=f2bf(a.x); r[1]=f2bf(a.y); r[2]=f2bf(a.z); r[3]=f2bf(a.w);
  r[4]=f2bf(b.x); r[5]=f2bf(b.y); r[6]=f2bf(b.z); r[7]=f2bf(b.w);
  return r;
}
// non-temporal 16B load via ext_vector type (builtin rejects HIP_vector_type)
__device__ __forceinline__ float4 ntload4(const float* p){
  f32x4 v = __builtin_nontemporal_load((const f32x4*)p);
  return make_float4(v[0], v[1], v[2], v[3]);
}

// ---------------- small fp32->bf16 conversion: ann / W_att / W_pre only ----------------
// block ranges: [0,64) ann, [64,192) Watt, [192,448) Wpre
__global__ __launch_bounds__(256) void k_cvtsmall(
    const float* __restrict__ ann, const float* __restrict__ Watt, const float* __restrict__ Wpre,
    unsigned short* __restrict__ Annb, unsigned short* __restrict__ Wattb,
    unsigned short* __restrict__ Bpre, unsigned short* __restrict__ Wpcb)
{
  const int b = blockIdx.x;
  if (b >= 192) {      // W_pre split path (per-lane column split)
    unsigned base = (unsigned)(b-192)*8192u;
    #pragma unroll
    for (int it=0; it<4; ++it) {
      unsigned idx = base + ((unsigned)it*256u + threadIdx.x)*8u;
      const float* sp = Wpre + idx;
      unsigned row = idx >> 11, c = idx & 2047;
      unsigned short* dp = (c < 1024) ? (Bpre + (size_t)row*1536 + c) : (Wpcb + (size_t)row*1024 + (c-1024));
      float4 a = *(const float4*)sp, bb = *(const float4*)(sp+4);
      *(u16x8*)dp = pack8(a,bb);
    }
    return;
  }
  const float* src; unsigned short* dst;
  if (b < 64) { unsigned o=(unsigned)b*8192u;      src=ann+o;  dst=Annb+o; }
  else        { unsigned o=(unsigned)(b-64)*8192u; src=Watt+o; dst=Wattb+o; }
  const unsigned t8 = threadIdx.x*8u;
  #pragma unroll
  for (int it=0; it<4; ++it) {
    float4 a = *(const float4*)(src + it*2048 + t8);
    float4 bb = *(const float4*)(src + it*2048 + t8 + 4);
    *(u16x8*)(dst + it*2048 + t8) = pack8(a,bb);
  }
}

// ---------------- emb halves of all LSTM inputs (one-shot; tree topology is static) ----------------
__global__ __launch_bounds__(64) void k_emb(const float* __restrict__ emb, const int* __restrict__ values,
                                            unsigned short* __restrict__ Xb){
  int i = blockIdx.x + 1;                  // 1..255
  int lev, s;
  if (i < 5)       { lev=1; s=1; }
  else if (i < 21) { lev=2; s=5; }
  else if (i < 85) { lev=3; s=21; }
  else             { lev=4; s=85; }
  int p = (i-1)>>2, o = i - s;
  unsigned short* xr = Xb + ((size_t)(lev-1)*4*48 + (size_t)(o&3)*48 + (o>>2)) * 2560;
  const float* er = emb + (size_t)values[p]*512;
  int c = threadIdx.x*8;
  float4 a = *(const float4*)(er+c), b = *(const float4*)(er+c+4);
  *(u16x8*)(xr+c) = pack8(a,b);
}

// ---------------- root: C, XH h, and h into level-1 child slots ----------------
__global__ __launch_bounds__(256) void k_root(const float* __restrict__ rH, const float* __restrict__ rC,
                                              float* __restrict__ Cb, unsigned short* __restrict__ XH,
                                              unsigned short* __restrict__ Xb1){
  int u = threadIdx.x*4;
  float4 h = *(const float4*)(rH+u);
  float4 c = *(const float4*)(rC+u);
  *(float4*)(Cb+u) = c;
  u16x4 r; r[0]=f2bf(h.x); r[1]=f2bf(h.y); r[2]=f2bf(h.z); r[3]=f2bf(h.w);
  *(u16x4*)(XH+u) = r;
  #pragma unroll
  for (int k=0;k<4;++k)
    *(u16x4*)(Xb1 + (size_t)k*48*2560 + 1536 + u) = r;
}

// ---------------- full-K bf16 GEMM (AHV / ANWT prep) ----------------
template<int MT>
__global__ __launch_bounds__(256) void k_gemm_fb(
    const unsigned short* __restrict__ A, int astride,
    const unsigned short* __restrict__ B, int K,
    const float* __restrict__ bias,
    unsigned short* __restrict__ Cb16,
    int ostride, int coff, int N, int M)
{
  const int mb0 = blockIdx.y * (MT*16);
  const int wv = threadIdx.x >> 6, lane = threadIdx.x & 63;
  const int col = (blockIdx.x*4 + wv)*16 + (lane & 15);
  const int colc = min(col, N-1);
  const int khalf = (lane >> 4) * 8;

  f32x4 acc[MT];
  #pragma unroll
  for (int m = 0; m < MT; ++m) acc[m] = (f32x4){0.f,0.f,0.f,0.f};
  int arow[MT];
  #pragma unroll
  for (int m = 0; m < MT; ++m) arow[m] = min(mb0 + m*16 + (lane & 15), M-1);

  #pragma unroll 4
  for (int kk = 0; kk < K; kk += 32) {
    int kb = kk + khalf;
    s16x8 bfv = *(const s16x8*)(B + (size_t)colc*K + kb);
    #pragma unroll
    for (int m = 0; m < MT; ++m) {
      s16x8 af = *(const s16x8*)(A + (size_t)arow[m]*astride + kb);
      acc[m] = MFMA16(af, bfv, acc[m]);
    }
  }

  const int r0 = (lane >> 4) * 4;
  #pragma unroll
  for (int m = 0; m < MT; ++m) {
    #pragma unroll
    for (int q = 0; q < 4; ++q) {
      int row = mb0 + m*16 + r0 + q;
      if (row < M && col < N) {
        float v = acc[m][q] + (bias ? bias[col] : 0.f);
        Cb16[(size_t)row*ostride + col + coff] = f2bf(v);
      }
    }
  }
}

// ---------------- W_out GEMM: fp32 B staged+converted to LDS (NT loads, row-clamped) ----------------
__global__ __launch_bounds__(256) void k_wout(
    const unsigned short* __restrict__ A,      // Etb [256][1024]
    const float* __restrict__ B,               // W_out fp32 [10001][1024]
    const float* __restrict__ bias,
    unsigned short* __restrict__ Lgb)
{
  __shared__ unsigned short bs[16*1032];
  const int c0 = blockIdx.x*16;
  const int tid = threadIdx.x;
  #pragma unroll
  for (int it = 0; it < 8; ++it) {
    int e = it*2048 + tid*8;
    int row = e >> 10, ck = e & 1023;
    int rr = min(c0 + row, NCLS-1);
    const float* sp = B + (size_t)rr*1024 + ck;
    float4 a = ntload4(sp);
    float4 b = ntload4(sp+4);
    *(u16x8*)(bs + row*1032 + ck) = pack8(a,b);
  }
  __syncthreads();

  const int wv = tid >> 6, lane = tid & 63;
  const int col16 = lane & 15;
  const int khalf = (lane >> 4) * 8;
  const int mb0 = wv * 64;
  const int col = c0 + col16;

  f32x4 acc[4];
  #pragma unroll
  for (int m=0;m<4;++m) acc[m] = (f32x4){0.f,0.f,0.f,0.f};
  int arow[4];
  #pragma unroll
  for (int m=0;m<4;++m) arow[m] = mb0 + m*16 + col16;

  #pragma unroll 8
  for (int kk = 0; kk < 1024; kk += 32) {
    int kb = kk + khalf;
    s16x8 bfv = *(const s16x8*)(bs + col16*1032 + kb);
    #pragma unroll
    for (int m=0;m<4;++m) {
      s16x8 af = *(const s16x8*)(A + (size_t)arow[m]*1024 + kb);
      acc[m] = MFMA16(af, bfv, acc[m]);
    }
  }

  if (col < NCLS) {
    const int r0 = (lane >> 4) * 4;
    float bv = bias[col];
    #pragma unroll
    for (int m=0;m<4;++m) {
      #pragma unroll
      for (int q=0;q<4;++q) {
        int row = mb0 + m*16 + r0 + q;
        Lgb[(size_t)row*NCLS + col] = f2bf(acc[m][q] + bv);
      }
    }
  }
}

// ---------------- level-1 LSTM GEMM fused with weight conversion (fp32 NT read -> bf16 write + MFMA) ----------------
// grid (64, 5, 4): each (col,ks,slot) weight element touched exactly once; M=1 row per slot.
__global__ __launch_bounds__(256) void k_lstm1c(
    const unsigned short* __restrict__ A,      // Xb level-1 [4][48][2560]
    const float* __restrict__ B1f, const float* __restrict__ B2f,   // W_ih, W_hh fp32
    unsigned short* __restrict__ W1, unsigned short* __restrict__ W2,  // bf16 out
    float* __restrict__ P)
{
  const int z = blockIdx.z;
  const unsigned short* Az = A + (size_t)z*48*2560;
  const float* B1z = B1f + (size_t)z*4096*1536;
  const float* B2z = B2f + (size_t)z*4096*1024;
  unsigned short* W1z = W1 + (size_t)z*4096*1536;
  unsigned short* W2z = W2 + (size_t)z*4096*1024;
  const int ks = blockIdx.y;
  const int k0 = ks * 512;
  const int wv = threadIdx.x >> 6, lane = threadIdx.x & 63;
  const int col = (blockIdx.x*4 + wv)*16 + (lane & 15);   // exact 4096 coverage
  const int khalf = (lane >> 4) * 8;

  f32x4 acc = (f32x4){0.f,0.f,0.f,0.f};
  #pragma unroll 4
  for (int kk = 0; kk < 512; kk += 32) {
    int kb = k0 + kk + khalf;
    const float* bp; unsigned short* wp;
    if (kb < 1536) { bp = B1z + (size_t)col*1536 + kb;        wp = W1z + (size_t)col*1536 + kb; }
    else           { bp = B2z + (size_t)col*1024 + (kb-1536); wp = W2z + (size_t)col*1024 + (kb-1536); }
    float4 b0 = ntload4(bp);
    float4 b1 = ntload4(bp+4);
    u16x8 w = pack8(b0,b1);
    *(u16x8*)wp = w;
    s16x8 bfv;
    #pragma unroll
    for (int t=0;t<8;++t) bfv[t] = (short)w[t];
    s16x8 af = *(const s16x8*)(Az + kb);    // row 0 (M=1, all lanes clamped)
    acc = MFMA16(af, bfv, acc);
  }
  const int r0 = (lane >> 4) * 4;
  if (r0 == 0)    // only row 0 valid
    P[(((size_t)z*5 + ks)*48)*4096 + col] = acc[0];
}

// ---------------- split-K + slot-batched bf16 GEMM (LSTM levels 2-4), B split B1|B2 ----------------
template<int MT, int KITER>
__global__ __launch_bounds__(256) void k_gemm_skzb2(
    const unsigned short* __restrict__ A, int astride,
    const unsigned short* __restrict__ B1, int K1,
    const unsigned short* __restrict__ B2, int K2,
    float* __restrict__ P, int N, int Mbase, int Mpad,
    int aZ, int b1Z, int b2Z, int KS)
{
  const int z = blockIdx.z;
  const int M = (Mbase - z + 3) >> 2;
  const unsigned short* Az = A + (size_t)z*aZ;
  const unsigned short* B1z = B1 + (size_t)z*b1Z;
  const unsigned short* B2z = B2 + (size_t)z*b2Z;
  const int ks = blockIdx.y;
  const int k0 = ks * (KITER*32);
  const int wv = threadIdx.x >> 6, lane = threadIdx.x & 63;
  const int col = (blockIdx.x*4 + wv)*16 + (lane & 15);
  const int colc = min(col, N-1);
  const int khalf = (lane >> 4) * 8;

  f32x4 acc[MT];
  #pragma unroll
  for (int m = 0; m < MT; ++m) acc[m] = (f32x4){0.f,0.f,0.f,0.f};
  int arow[MT];
  #pragma unroll
  for (int m = 0; m < MT; ++m) arow[m] = min(m*16 + (lane & 15), M-1);

  #pragma unroll 8
  for (int kk = 0; kk < KITER*32; kk += 32) {
    int kb = k0 + kk + khalf;
    const unsigned short* bp = (kb < K1) ? (B1z + (size_t)colc*K1 + kb)
                                         : (B2z + (size_t)colc*K2 + (kb - K1));
    s16x8 bfv = *(const s16x8*)bp;
    #pragma unroll
    for (int m = 0; m < MT; ++m) {
      s16x8 af = *(const s16x8*)(Az + (size_t)arow[m]*astride + kb);
      acc[m] = MFMA16(af, bfv, acc[m]);
    }
  }

  const int r0 = (lane >> 4) * 4;
  #pragma unroll
  for (int m = 0; m < MT; ++m) {
    #pragma unroll
    for (int q = 0; q < 4; ++q) {
      int row = m*16 + r0 + q;
      if (row < M && col < N)
        P[(((size_t)z*KS + ks)*Mpad + row)*N + col] = acc[m][q];
    }
  }
}

// ---------------- small split-K bf16 GEMM (chunk 128): P[ks][M][N] ----------------
template<int MT>
__global__ __launch_bounds__(256) void k_gemm_skb(
    const unsigned short* __restrict__ A, int astride,
    const unsigned short* __restrict__ B, int K,
    float* __restrict__ P, int N, int M)
{
  const int ks = blockIdx.y;
  const int k0 = ks * 128;
  const int wv = threadIdx.x >> 6, lane = threadIdx.x & 63;
  const int col = (blockIdx.x*4 + wv)*16 + (lane & 15);
  const int colc = min(col, N-1);
  const int khalf = (lane >> 4) * 8;

  f32x4 acc[MT];
  #pragma unroll
  for (int m = 0; m < MT; ++m) acc[m] = (f32x4){0.f,0.f,0.f,0.f};
  int arow[MT];
  #pragma unroll
  for (int m = 0; m < MT; ++m) arow[m] = min(m*16 + (lane & 15), M-1);

  #pragma unroll
  for (int kk = 0; kk < 128; kk += 32) {
    int kb = k0 + kk + khalf;
    s16x8 bfv = *(const s16x8*)(B + (size_t)colc*K + kb);
    #pragma unroll
    for (int m = 0; m < MT; ++m) {
      s16x8 af = *(const s16x8*)(A + (size_t)arow[m]*astride + kb);
      acc[m] = MFMA16(af, bfv, acc[m]);
    }
  }

  const int r0 = (lane >> 4) * 4;
  #pragma unroll
  for (int m = 0; m < MT; ++m) {
    #pragma unroll
    for (int q = 0; q < 4; ++q) {
      int row = m*16 + r0 + q;
      if (row < M && col < N)
        P[((size_t)ks*M + row)*N + col] = acc[m][q];
    }
  }
}

// ---------------- fused split-K sum + softmax over 512 logits -> bf16 probs into XH[.][1024:1536] ----------------
__global__ __launch_bounds__(256) void k_soft(const float* __restrict__ P, int KS, int M,
                                              unsigned short* __restrict__ dst)  // XH + s*1536 + 1024
{
  __shared__ float sm[512];
  __shared__ float red[8];
  const int m = blockIdx.x;
  const int tid = threadIdx.x, wv = tid>>6, ln = tid&63;
  for (int l = tid; l < 512; l += 256) {
    float s = 0.f;
    for (int ks = 0; ks < KS; ++ks) s += P[((size_t)ks*M + m)*512 + l];
    sm[l] = s;
  }
  __syncthreads();
  float mx = -1e30f;
  for (int l=tid; l<512; l+=256) mx = fmaxf(mx, sm[l]);
  #pragma unroll
  for (int o=32;o;o>>=1) mx = fmaxf(mx, __shfl_xor(mx,o,64));
  if (ln==0) red[wv]=mx;
  __syncthreads();
  mx = fmaxf(fmaxf(red[0],red[1]),fmaxf(red[2],red[3]));
  float se = 0.f;
  for (int l=tid; l<512; l+=256){ float ev=__expf(sm[l]-mx); sm[l]=ev; se+=ev; }
  __syncthreads();
  #pragma unroll
  for (int o=32;o;o>>=1) se += __shfl_xor(se,o,64);
  if (ln==0) red[wv]=se;
  __syncthreads();
  float invS = 1.f/(red[0]+red[1]+red[2]+red[3]);
  for (int l=tid; l<512; l+=256) dst[(size_t)m*1536 + l] = f2bf(sm[l]*invS);
}

// ---------------- et reduction: block per row; tanh; write Etb + scatter to children Xb ----------------
__global__ __launch_bounds__(256) void k_red4(const float* __restrict__ P, int KS, int M,
                                              const float* __restrict__ bias,
                                              unsigned short* __restrict__ Etb, int s,
                                              int snext, unsigned short* __restrict__ XbNext)
{
  const int row = blockIdx.x;
  const int col = threadIdx.x*4;
  float4 sum = *(const float4*)(bias + col);
  for (int ks = 0; ks < KS; ++ks) {
    float4 p = *(const float4*)(P + ((size_t)ks*M + row)*1024 + col);
    sum.x += p.x; sum.y += p.y; sum.z += p.z; sum.w += p.w;
  }
  u16x4 r;
  r[0]=f2bf(tanhfast(sum.x)); r[1]=f2bf(tanhfast(sum.y));
  r[2]=f2bf(tanhfast(sum.z)); r[3]=f2bf(tanhfast(sum.w));
  *(u16x4*)(Etb + (size_t)(s+row)*1024 + col) = r;
  if (XbNext) {
    int cbase = 4*(s+row) + 1;
    #pragma unroll
    for (int k=0;k<4;++k) {
      int cn = cbase + k;
      if (cn < 256) {
        int o = cn - snext;
        *(u16x4*)(XbNext + ((size_t)(o&3)*48 + (o>>2))*2560 + 512 + col) = r;
      }
    }
  }
}

// ---------------- LSTM epilogue: gates -> h,c; scatter h to children Xb ----------------
__global__ __launch_bounds__(256) void k_epi(const float* __restrict__ P,
                                             const float* __restrict__ b_ih, const float* __restrict__ b_hh,
                                             float* __restrict__ Cb, unsigned short* __restrict__ XH,
                                             int s, int snext, unsigned short* __restrict__ XbNext){
  int i = s + blockIdx.x;
  int slot = (i - s) & 3, j = (i - s) >> 2;
  int p = (i - 1) >> 2;
  const float* bi = b_ih + (size_t)slot*4096;
  const float* bh = b_hh + (size_t)slot*4096;
  const int u = threadIdx.x*4;

  float4 ig, fg, gg, og;
  {
    float4 a, b;
    a = *(const float4*)(bi+u);      b = *(const float4*)(bh+u);      ig = make_float4(a.x+b.x,a.y+b.y,a.z+b.z,a.w+b.w);
    a = *(const float4*)(bi+1024+u); b = *(const float4*)(bh+1024+u); fg = make_float4(a.x+b.x,a.y+b.y,a.z+b.z,a.w+b.w);
    a = *(const float4*)(bi+2048+u); b = *(const float4*)(bh+2048+u); gg = make_float4(a.x+b.x,a.y+b.y,a.z+b.z,a.w+b.w);
    a = *(const float4*)(bi+3072+u); b = *(const float4*)(bh+3072+u); og = make_float4(a.x+b.x,a.y+b.y,a.z+b.z,a.w+b.w);
  }
  #pragma unroll
  for (int ks = 0; ks < 5; ++ks) {
    const float* g = P + (((size_t)slot*5 + ks)*48 + j)*4096;
    float4 a;
    a = *(const float4*)(g+u);      ig.x+=a.x; ig.y+=a.y; ig.z+=a.z; ig.w+=a.w;
    a = *(const float4*)(g+1024+u); fg.x+=a.x; fg.y+=a.y; fg.z+=a.z; fg.w+=a.w;
    a = *(const float4*)(g+2048+u); gg.x+=a.x; gg.y+=a.y; gg.z+=a.z; gg.w+=a.w;
    a = *(const float4*)(g+3072+u); og.x+=a.x; og.y+=a.y; og.z+=a.z; og.w+=a.w;
  }
  float4 cp = *(const float4*)(Cb + (size_t)p*1024 + u);
  float4 cc, hh;
  cc.x = sigf(fg.x)*cp.x + sigf(ig.x)*tanhfast(gg.x); hh.x = sigf(og.x)*tanhfast(cc.x);
  cc.y = sigf(fg.y)*cp.y + sigf(ig.y)*tanhfast(gg.y); hh.y = sigf(og.y)*tanhfast(cc.y);
  cc.z = sigf(fg.z)*cp.z + sigf(ig.z)*tanhfast(gg.z); hh.z = sigf(og.z)*tanhfast(cc.z);
  cc.w = sigf(fg.w)*cp.w + sigf(ig.w)*tanhfast(gg.w); hh.w = sigf(og.w)*tanhfast(cc.w);
  *(float4*)(Cb + (size_t)i*1024 + u) = cc;
  u16x4 r; r[0]=f2bf(hh.x); r[1]=f2bf(hh.y); r[2]=f2bf(hh.z); r[3]=f2bf(hh.w);
  *(u16x4*)(XH + (size_t)i*1536 + u) = r;
  if (XbNext) {
    int cbase = 4*i + 1;
    #pragma unroll
    for (int k=0;k<4;++k) {
      int cn = cbase + k;
      if (cn < 256) {
        int o = cn - snext;
        *(u16x4*)(XbNext + ((size_t)(o&3)*48 + (o>>2))*2560 + 1536 + u) = r;
      }
    }
  }
}

// ---------------- loss per node (bf16 logits, register-cached single read) ----------------
__global__ __launch_bounds__(256) void k_loss(const unsigned short* __restrict__ Lgb,
                                              const int* __restrict__ values,
                                              float* __restrict__ Nl)
{
  __shared__ float red[8];
  const int node = blockIdx.x;
  const int tid = threadIdx.x, wv = tid>>6, ln = tid&63;
  const unsigned short* lg = Lgb + (size_t)node*NCLS;

  u16x8 v0 = *(const u16x8*)(lg + 0*2048 + tid*8);
  u16x8 v1 = *(const u16x8*)(lg + 1*2048 + tid*8);
  u16x8 v2 = *(const u16x8*)(lg + 2*2048 + tid*8);
  u16x8 v3 = *(const u16x8*)(lg + 3*2048 + tid*8);
  u16x8 v4;
  {
    int e = 8192 + tid*8;
    #pragma unroll
    for (int k=0;k<8;++k) v4[k] = (e+k < NCLS) ? lg[e+k] : (unsigned short)0xFF80;
  }

  float m = -1e30f;
  #pragma unroll
  for (int k=0;k<8;++k){
    m = fmaxf(m, bf2f(v0[k])); m = fmaxf(m, bf2f(v1[k]));
    m = fmaxf(m, bf2f(v2[k])); m = fmaxf(m, bf2f(v3[k]));
    m = fmaxf(m, bf2f(v4[k]));
  }
  #pragma unroll
  for (int o=32;o;o>>=1) m = fmaxf(m, __shfl_xor(m,o,64));
  if (ln==0) red[wv]=m;
  __syncthreads();
  m = fmaxf(fmaxf(red[0],red[1]),fmaxf(red[2],red[3]));
  __syncthreads();

  float s = 0.f;
  #pragma unroll
  for (int k=0;k<8;++k){
    s += __expf(bf2f(v0[k])-m); s += __expf(bf2f(v1[k])-m);
    s += __expf(bf2f(v2[k])-m); s += __expf(bf2f(v3[k])-m);
    s += __expf(bf2f(v4[k])-m);
  }
  #pragma unroll
  for (int o=32;o;o>>=1) s += __shfl_xor(s,o,64);
  if (ln==0) red[wv]=s;
  __syncthreads();
  s = red[0]+red[1]+red[2]+red[3];
  __syncthreads();
  float invs = 1.f/s;

  float q = 0.f;
  #pragma unroll
  for (int k=0;k<8;++k){
    q += __expf(__expf(bf2f(v0[k])-m)*invs);
    q += __expf(__expf(bf2f(v1[k])-m)*invs);
    q += __expf(__expf(bf2f(v2[k])-m)*invs);
    q += __expf(__expf(bf2f(v3[k])-m)*invs);
    if (8192 + tid*8 + k < NCLS) q += __expf(__expf(bf2f(v4[k])-m)*invs);
  }
  #pragma unroll
  for (int o=32;o;o>>=1) q += __shfl_xor(q,o,64);
  if (ln==0) red[wv]=q;
  __syncthreads();
  if (tid==0) {
    float qq = red[0]+red[1]+red[2]+red[3];
    int v = values[node];
    float pv = __expf(bf2f(lg[v])-m)*invs;
    float nl = __logf(qq) - pv;
    if (v == NCLS-1) nl *= 0.2f;
    Nl[node] = nl;
  }
}

__global__ __launch_bounds__(256) void k_final(const float* __restrict__ Nl, float* __restrict__ out){
  __shared__ float red[8];
  int tid = threadIdx.x, wv = tid>>6, ln = tid&63;
  float s = Nl[tid];
  #pragma unroll
  for (int o=32;o;o>>=1) s += __shfl_xor(s,o,64);
  if (ln==0) red[wv]=s;
  __syncthreads();
  if (tid==0) out[0] = red[0]+red[1]+red[2]+red[3];
}

static inline void gemm_skb(hipStream_t st, int MT, const unsigned short* A, int astride,
                            const unsigned short* B, int K, float* P, int N, int M)
{
  dim3 grid(N/64, K/128);
  #define SKCASE(MTv) k_gemm_skb<MTv><<<grid, 256, 0, st>>>(A,astride,B,K,P,N,M)
  switch(MT){
    case 1:  SKCASE(1);  break;
    case 4:  SKCASE(4);  break;
    case 11: SKCASE(11); break;
    default: SKCASE(16); break;
  }
  #undef SKCASE
}

extern "C" void kernel_launch(void* const* d_in, const int* in_sizes, int n_in,
                              void* d_out, int out_size, void* d_ws, size_t ws_size,
                              hipStream_t stream)
{
  const float* rootH = (const float*)d_in[0];
  const float* rootC = (const float*)d_in[1];
  const float* ann   = (const float*)d_in[2];
  const int*   values= (const int*)d_in[3];
  const float* emb   = (const float*)d_in[6];
  const float* W_ih  = (const float*)d_in[7];
  const float* W_hh  = (const float*)d_in[8];
  const float* b_ih  = (const float*)d_in[9];
  const float* b_hh  = (const float*)d_in[10];
  const float* W_att = (const float*)d_in[11];
  const float* b_att = (const float*)d_in[12];
  const float* W_pre = (const float*)d_in[13];
  const float* b_pre = (const float*)d_in[14];
  const float* W_out = (const float*)d_in[15];
  const float* b_out = (const float*)d_in[16];

  float* ws = (float*)d_ws;
  float* Cb  = ws; ws += 256*1024;              // fp32 c
  float* Nl  = ws; ws += 256;
  float* PB  = ws; ws += 4*5*48*4096;           // shared split-K partials
  unsigned short* Wbih  = (unsigned short*)ws;  // bf16 [4][4096][1536]
  unsigned short* Wbhh  = Wbih  + (size_t)4*4096*1536;   // bf16 [4][4096][1024]
  unsigned short* Wattb = Wbhh  + (size_t)4*4096*1024;   // bf16 [1024][1024]
  unsigned short* Bpre  = Wattb + 1024*1024;    // bf16 [1024][1536] = [W_pre_h | ANWT]
  unsigned short* Wpcb  = Bpre  + 1024*1536;    // bf16 [1024][1024] W_pre ctx half
  unsigned short* AHVb  = Wpcb  + 1024*1024;    // bf16 [512][1024]
  unsigned short* Annb  = AHVb  + 512*1024;     // bf16 [512][1024]
  unsigned short* XH    = Annb  + 512*1024;     // bf16 [256][1536] = [h | probs]
  unsigned short* Etb   = XH    + 256*1536;     // bf16 [256][1024]
  unsigned short* Xb    = Etb   + 256*1024;     // bf16 [4 levels][4][48][2560]
  unsigned short* Lgb   = Xb    + (size_t)4*4*48*2560;   // bf16 [256][10001] logits

  // ---- one-time prep ----
  k_cvtsmall<<<448, 256, 0, stream>>>(ann, W_att, W_pre, Annb, Wattb, Bpre, Wpcb);
  k_emb   <<<255,  64,  0, stream>>>(emb, values, Xb);
  // AHV = ann @ W_att^T + b_att  (bf16 out)
  k_gemm_fb<4><<<dim3(16,8), 256, 0, stream>>>(Annb, 1024, Wattb, 1024, b_att, AHVb, 1024, 0, 1024, 512);
  // ANWT[out][l] = W_pre_ctx[out]·ann[l] -> Bpre[out][1024:1536]
  k_gemm_fb<4><<<dim3(8,16), 256, 0, stream>>>(Wpcb, 1024, Annb, 1024, nullptr, Bpre, 1536, 1024, 512, 1024);
  k_root<<<1, 256, 0, stream>>>(rootH, rootC, Cb, XH, Xb);

  const int LS[6] = {0,1,5,21,85,256};
  for (int lev=0; lev<5; ++lev){
    int s=LS[lev], e=LS[lev+1], n=e-s;
    unsigned short* XbL = Xb + (size_t)(lev-1)*4*48*2560;       // this level's LSTM input (lev>=1)
    unsigned short* XbN = (lev<4) ? (Xb + (size_t)lev*4*48*2560) : nullptr;  // children's
    int snext = (lev<4) ? LS[lev+1] : 0;
    if (lev==1){
      // fused: convert W_ih/W_hh fp32 -> bf16 (NT read) while computing level-1 gates
      k_lstm1c<<<dim3(64,5,4),256,0,stream>>>(XbL, W_ih, W_hh, Wbih, Wbhh, PB);
      k_epi<<<n,256,0,stream>>>(PB, b_ih, b_hh, Cb, XH, s, snext, XbN);
    } else if (lev>1){
      if (lev==4)
        k_gemm_skzb2<3,16><<<dim3(64,5,4),256,0,stream>>>(XbL, 2560, Wbih, 1536, Wbhh, 1024, PB,
            4096, n, 48, 48*2560, 4096*1536, 4096*1024, 5);
      else
        k_gemm_skzb2<1,16><<<dim3(64,5,4),256,0,stream>>>(XbL, 2560, Wbih, 1536, Wbhh, 1024, PB,
            4096, n, 48, 48*2560, 4096*1536, 4096*1024, 5);
      k_epi<<<n,256,0,stream>>>(PB, b_ih, b_hh, Cb, XH, s, snext, XbN);
    }
    int mtn = (n+15)/16;
    // attention logits [n x 512] = h · AHV^T (split-K MFMA) + fused softmax -> probs in XH
    gemm_skb(stream, mtn, XH + (size_t)s*1536, 1536, AHVb, 1024, PB, 512, n);
    k_soft<<<n,256,0,stream>>>(PB, 8, n, XH + (size_t)s*1536 + 1024);
    // et = tanh([h|probs] · Bpre^T + b_pre): split-K + per-row reduce (+ scatter to children Xb)
    gemm_skb(stream, mtn, XH + (size_t)s*1536, 1536, Bpre, 1536, PB, 1024, n);
    k_red4<<<n,256,0,stream>>>(PB, 12, n, b_pre, Etb, s, snext, XbN);
  }

  // W_out logits: fp32 B staged->LDS with convert (NT), bf16 output
  k_wout<<<626, 256, 0, stream>>>(Etb, W_out, b_out, Lgb);
  k_loss <<<256,256,0,stream>>>(Lgb, values, Nl);
  k_final<<<1,  256,0,stream>>>(Nl, (float*)d_out);
}

// Round 18
// 395.406 us; speedup vs baseline: 1.0055x; 1.0003x over previous
//
#include <hip/hip_runtime.h>
#include <hip/hip_bf16.h>
#include <math.h>

#define HD 1024
#define NCLS 10001

typedef short s16x8 __attribute__((ext_vector_type(8)));
typedef unsigned short u16x8 __attribute__((ext_vector_type(8)));
typedef unsigned short u16x4 __attribute__((ext_vector_type(4)));
typedef float f32x4 __attribute__((ext_vector_type(4)));
#define MFMA16(a_, b_, c_) __builtin_amdgcn_mfma_f32_16x16x32_bf16((a_), (b_), (c_), 0, 0, 0)

__device__ __forceinline__ float sigf(float x){ return 1.f/(1.f+__expf(-x)); }
__device__ __forceinline__ float tanhfast(float x){
  x = fminf(fmaxf(x,-10.f),10.f);
  float e2 = __expf(2.f*x);
  return (e2-1.f)/(e2+1.f);
}
__device__ __forceinline__ unsigned short f2bf(float f){
  unsigned int u = __float_as_uint(f);
  u += 0x7FFF + ((u >> 16) & 1);          // round-to-nearest-even
  return (unsigned short)(u >> 16);
}
__device__ __forceinline__ float bf2f(unsigned short u){
  return __uint_as_float(((unsigned)u) << 16);
}
__device__ __forceinline__ u16x8 pack8(float4 a, float4 b){
  u16x8 r;
  r[0]=f2bf(a.x); r[1]=f2bf(a.y); r[2]=f2bf(a.z); r[3]=f2bf(a.w);
  r[4]=f2bf(b.x); r[5]=f2bf(b.y); r[6]=f2bf(b.z); r[7]=f2bf(b.w);
  return r;
}
// non-temporal 16B load via ext_vector type (builtin rejects HIP_vector_type)
__device__ __forceinline__ float4 ntload4(const float* p){
  f32x4 v = __builtin_nontemporal_load((const f32x4*)p);
  return make_float4(v[0], v[1], v[2], v[3]);
}

// ---------------- small fp32->bf16 conversion: ann / W_att / W_pre only ----------------
// block ranges: [0,64) ann, [64,192) Watt, [192,448) Wpre
__global__ __launch_bounds__(256) void k_cvtsmall(
    const float* __restrict__ ann, const float* __restrict__ Watt, const float* __restrict__ Wpre,
    unsigned short* __restrict__ Annb, unsigned short* __restrict__ Wattb,
    unsigned short* __restrict__ Bpre, unsigned short* __restrict__ Wpcb)
{
  const int b = blockIdx.x;
  if (b >= 192) {      // W_pre split path (per-lane column split)
    unsigned base = (unsigned)(b-192)*8192u;
    #pragma unroll
    for (int it=0; it<4; ++it) {
      unsigned idx = base + ((unsigned)it*256u + threadIdx.x)*8u;
      const float* sp = Wpre + idx;
      unsigned row = idx >> 11, c = idx & 2047;
      unsigned short* dp = (c < 1024) ? (Bpre + (size_t)row*1536 + c) : (Wpcb + (size_t)row*1024 + (c-1024));
      float4 a = *(const float4*)sp, bb = *(const float4*)(sp+4);
      *(u16x8*)dp = pack8(a,bb);
    }
    return;
  }
  const float* src; unsigned short* dst;
  if (b < 64) { unsigned o=(unsigned)b*8192u;      src=ann+o;  dst=Annb+o; }
  else        { unsigned o=(unsigned)(b-64)*8192u; src=Watt+o; dst=Wattb+o; }
  const unsigned t8 = threadIdx.x*8u;
  #pragma unroll
  for (int it=0; it<4; ++it) {
    float4 a = *(const float4*)(src + it*2048 + t8);
    float4 bb = *(const float4*)(src + it*2048 + t8 + 4);
    *(u16x8*)(dst + it*2048 + t8) = pack8(a,bb);
  }
}

// ---------------- emb halves of all LSTM inputs (one-shot; tree topology is static) ----------------
__global__ __launch_bounds__(64) void k_emb(const float* __restrict__ emb, const int* __restrict__ values,
                                            unsigned short* __restrict__ Xb){
  int i = blockIdx.x + 1;                  // 1..255
  int lev, s;
  if (i < 5)       { lev=1; s=1; }
  else if (i < 21) { lev=2; s=5; }
  else if (i < 85) { lev=3; s=21; }
  else             { lev=4; s=85; }
  int p = (i-1)>>2, o = i - s;
  unsigned short* xr = Xb + ((size_t)(lev-1)*4*48 + (size_t)(o&3)*48 + (o>>2)) * 2560;
  const float* er = emb + (size_t)values[p]*512;
  int c = threadIdx.x*8;
  float4 a = *(const float4*)(er+c), b = *(const float4*)(er+c+4);
  *(u16x8*)(xr+c) = pack8(a,b);
}

// ---------------- root: C, XH h, and h into level-1 child slots ----------------
__global__ __launch_bounds__(256) void k_root(const float* __restrict__ rH, const float* __restrict__ rC,
                                              float* __restrict__ Cb, unsigned short* __restrict__ XH,
                                              unsigned short* __restrict__ Xb1){
  int u = threadIdx.x*4;
  float4 h = *(const float4*)(rH+u);
  float4 c = *(const float4*)(rC+u);
  *(float4*)(Cb+u) = c;
  u16x4 r; r[0]=f2bf(h.x); r[1]=f2bf(h.y); r[2]=f2bf(h.z); r[3]=f2bf(h.w);
  *(u16x4*)(XH+u) = r;
  #pragma unroll
  for (int k=0;k<4;++k)
    *(u16x4*)(Xb1 + (size_t)k*48*2560 + 1536 + u) = r;
}

// ---------------- full-K bf16 GEMM (AHV / ANWT prep) ----------------
template<int MT>
__global__ __launch_bounds__(256) void k_gemm_fb(
    const unsigned short* __restrict__ A, int astride,
    const unsigned short* __restrict__ B, int K,
    const float* __restrict__ bias,
    unsigned short* __restrict__ Cb16,
    int ostride, int coff, int N, int M)
{
  const int mb0 = blockIdx.y * (MT*16);
  const int wv = threadIdx.x >> 6, lane = threadIdx.x & 63;
  const int col = (blockIdx.x*4 + wv)*16 + (lane & 15);
  const int colc = min(col, N-1);
  const int khalf = (lane >> 4) * 8;

  f32x4 acc[MT];
  #pragma unroll
  for (int m = 0; m < MT; ++m) acc[m] = (f32x4){0.f,0.f,0.f,0.f};
  int arow[MT];
  #pragma unroll
  for (int m = 0; m < MT; ++m) arow[m] = min(mb0 + m*16 + (lane & 15), M-1);

  #pragma unroll 4
  for (int kk = 0; kk < K; kk += 32) {
    int kb = kk + khalf;
    s16x8 bfv = *(const s16x8*)(B + (size_t)colc*K + kb);
    #pragma unroll
    for (int m = 0; m < MT; ++m) {
      s16x8 af = *(const s16x8*)(A + (size_t)arow[m]*astride + kb);
      acc[m] = MFMA16(af, bfv, acc[m]);
    }
  }

  const int r0 = (lane >> 4) * 4;
  #pragma unroll
  for (int m = 0; m < MT; ++m) {
    #pragma unroll
    for (int q = 0; q < 4; ++q) {
      int row = mb0 + m*16 + r0 + q;
      if (row < M && col < N) {
        float v = acc[m][q] + (bias ? bias[col] : 0.f);
        Cb16[(size_t)row*ostride + col + coff] = f2bf(v);
      }
    }
  }
}

// ---------------- W_out GEMM: fp32 B staged+converted to LDS (regular loads — W_out is L3-hot across replays) ----------------
__global__ __launch_bounds__(256) void k_wout(
    const unsigned short* __restrict__ A,      // Etb [256][1024]
    const float* __restrict__ B,               // W_out fp32 [10001][1024]
    const float* __restrict__ bias,
    unsigned short* __restrict__ Lgb)
{
  __shared__ unsigned short bs[16*1032];
  const int c0 = blockIdx.x*16;
  const int tid = threadIdx.x;
  #pragma unroll
  for (int it = 0; it < 8; ++it) {
    int e = it*2048 + tid*8;
    int row = e >> 10, ck = e & 1023;
    int rr = min(c0 + row, NCLS-1);
    const float* sp = B + (size_t)rr*1024 + ck;
    float4 a = *(const float4*)sp;
    float4 b = *(const float4*)(sp+4);
    *(u16x8*)(bs + row*1032 + ck) = pack8(a,b);
  }
  __syncthreads();

  const int wv = tid >> 6, lane = tid & 63;
  const int col16 = lane & 15;
  const int khalf = (lane >> 4) * 8;
  const int mb0 = wv * 64;
  const int col = c0 + col16;

  f32x4 acc[4];
  #pragma unroll
  for (int m=0;m<4;++m) acc[m] = (f32x4){0.f,0.f,0.f,0.f};
  int arow[4];
  #pragma unroll
  for (int m=0;m<4;++m) arow[m] = mb0 + m*16 + col16;

  #pragma unroll 8
  for (int kk = 0; kk < 1024; kk += 32) {
    int kb = kk + khalf;
    s16x8 bfv = *(const s16x8*)(bs + col16*1032 + kb);
    #pragma unroll
    for (int m=0;m<4;++m) {
      s16x8 af = *(const s16x8*)(A + (size_t)arow[m]*1024 + kb);
      acc[m] = MFMA16(af, bfv, acc[m]);
    }
  }

  if (col < NCLS) {
    const int r0 = (lane >> 4) * 4;
    float bv = bias[col];
    #pragma unroll
    for (int m=0;m<4;++m) {
      #pragma unroll
      for (int q=0;q<4;++q) {
        int row = mb0 + m*16 + r0 + q;
        Lgb[(size_t)row*NCLS + col] = f2bf(acc[m][q] + bv);
      }
    }
  }
}

// ---------------- level-1 LSTM GEMM fused with weight conversion (fp32 NT read -> bf16 write + MFMA) ----------------
// grid (64, 10, 4): chunk 256 along K; each (col,ks,slot) weight element touched exactly once; M=1 row per slot.
__global__ __launch_bounds__(256) void k_lstm1c(
    const unsigned short* __restrict__ A,      // Xb level-1 [4][48][2560]
    const float* __restrict__ B1f, const float* __restrict__ B2f,   // W_ih, W_hh fp32
    unsigned short* __restrict__ W1, unsigned short* __restrict__ W2,  // bf16 out
    float* __restrict__ P)
{
  const int z = blockIdx.z;
  const unsigned short* Az = A + (size_t)z*48*2560;
  const float* B1z = B1f + (size_t)z*4096*1536;
  const float* B2z = B2f + (size_t)z*4096*1024;
  unsigned short* W1z = W1 + (size_t)z*4096*1536;
  unsigned short* W2z = W2 + (size_t)z*4096*1024;
  const int ks = blockIdx.y;
  const int k0 = ks * 256;
  const int wv = threadIdx.x >> 6, lane = threadIdx.x & 63;
  const int col = (blockIdx.x*4 + wv)*16 + (lane & 15);   // exact 4096 coverage
  const int khalf = (lane >> 4) * 8;

  f32x4 acc = (f32x4){0.f,0.f,0.f,0.f};
  #pragma unroll
  for (int g = 0; g < 4; ++g) {
    int kbA = k0 + g*64 + khalf;
    int kbB = kbA + 32;
    const float* bpA; unsigned short* wpA;
    const float* bpB; unsigned short* wpB;
    if (kbA < 1536) { bpA = B1z + (size_t)col*1536 + kbA;        wpA = W1z + (size_t)col*1536 + kbA; }
    else            { bpA = B2z + (size_t)col*1024 + (kbA-1536); wpA = W2z + (size_t)col*1024 + (kbA-1536); }
    if (kbB < 1536) { bpB = B1z + (size_t)col*1536 + kbB;        wpB = W1z + (size_t)col*1536 + kbB; }
    else            { bpB = B2z + (size_t)col*1024 + (kbB-1536); wpB = W2z + (size_t)col*1024 + (kbB-1536); }
    float4 a0 = ntload4(bpA), a1 = ntload4(bpA+4);
    float4 c0v = ntload4(bpB), c1 = ntload4(bpB+4);
    asm volatile("" :: "v"(a0.x), "v"(a1.x), "v"(c0v.x), "v"(c1.x));   // both load-pairs in flight
    u16x8 wA = pack8(a0,a1);
    *(u16x8*)wpA = wA;
    u16x8 wB = pack8(c0v,c1);
    *(u16x8*)wpB = wB;
    s16x8 bfA, bfB;
    #pragma unroll
    for (int t=0;t<8;++t){ bfA[t] = (short)wA[t]; bfB[t] = (short)wB[t]; }
    s16x8 afA = *(const s16x8*)(Az + kbA);    // row 0 (M=1)
    s16x8 afB = *(const s16x8*)(Az + kbB);
    acc = MFMA16(afA, bfA, acc);
    acc = MFMA16(afB, bfB, acc);
  }
  const int r0 = (lane >> 4) * 4;
  if (r0 == 0)    // only row 0 valid
    P[(((size_t)z*10 + ks)*48)*4096 + col] = acc[0];
}

// ---------------- split-K + slot-batched bf16 GEMM (LSTM levels 2-4), B split B1|B2 ----------------
template<int MT, int KITER>
__global__ __launch_bounds__(256) void k_gemm_skzb2(
    const unsigned short* __restrict__ A, int astride,
    const unsigned short* __restrict__ B1, int K1,
    const unsigned short* __restrict__ B2, int K2,
    float* __restrict__ P, int N, int Mbase, int Mpad,
    int aZ, int b1Z, int b2Z, int KS)
{
  const int z = blockIdx.z;
  const int M = (Mbase - z + 3) >> 2;
  const unsigned short* Az = A + (size_t)z*aZ;
  const unsigned short* B1z = B1 + (size_t)z*b1Z;
  const unsigned short* B2z = B2 + (size_t)z*b2Z;
  const int ks = blockIdx.y;
  const int k0 = ks * (KITER*32);
  const int wv = threadIdx.x >> 6, lane = threadIdx.x & 63;
  const int col = (blockIdx.x*4 + wv)*16 + (lane & 15);
  const int colc = min(col, N-1);
  const int khalf = (lane >> 4) * 8;

  f32x4 acc[MT];
  #pragma unroll
  for (int m = 0; m < MT; ++m) acc[m] = (f32x4){0.f,0.f,0.f,0.f};
  int arow[MT];
  #pragma unroll
  for (int m = 0; m < MT; ++m) arow[m] = min(m*16 + (lane & 15), M-1);

  #pragma unroll 8
  for (int kk = 0; kk < KITER*32; kk += 32) {
    int kb = k0 + kk + khalf;
    const unsigned short* bp = (kb < K1) ? (B1z + (size_t)colc*K1 + kb)
                                         : (B2z + (size_t)colc*K2 + (kb - K1));
    s16x8 bfv = *(const s16x8*)bp;
    #pragma unroll
    for (int m = 0; m < MT; ++m) {
      s16x8 af = *(const s16x8*)(Az + (size_t)arow[m]*astride + kb);
      acc[m] = MFMA16(af, bfv, acc[m]);
    }
  }

  const int r0 = (lane >> 4) * 4;
  #pragma unroll
  for (int m = 0; m < MT; ++m) {
    #pragma unroll
    for (int q = 0; q < 4; ++q) {
      int row = m*16 + r0 + q;
      if (row < M && col < N)
        P[(((size_t)z*KS + ks)*Mpad + row)*N + col] = acc[m][q];
    }
  }
}

// ---------------- small split-K bf16 GEMM (chunk 128): P[ks][M][N] ----------------
template<int MT>
__global__ __launch_bounds__(256) void k_gemm_skb(
    const unsigned short* __restrict__ A, int astride,
    const unsigned short* __restrict__ B, int K,
    float* __restrict__ P, int N, int M)
{
  const int ks = blockIdx.y;
  const int k0 = ks * 128;
  const int wv = threadIdx.x >> 6, lane = threadIdx.x & 63;
  const int col = (blockIdx.x*4 + wv)*16 + (lane & 15);
  const int colc = min(col, N-1);
  const int khalf = (lane >> 4) * 8;

  f32x4 acc[MT];
  #pragma unroll
  for (int m = 0; m < MT; ++m) acc[m] = (f32x4){0.f,0.f,0.f,0.f};
  int arow[MT];
  #pragma unroll
  for (int m = 0; m < MT; ++m) arow[m] = min(m*16 + (lane & 15), M-1);

  #pragma unroll
  for (int kk = 0; kk < 128; kk += 32) {
    int kb = k0 + kk + khalf;
    s16x8 bfv = *(const s16x8*)(B + (size_t)colc*K + kb);
    #pragma unroll
    for (int m = 0; m < MT; ++m) {
      s16x8 af = *(const s16x8*)(A + (size_t)arow[m]*astride + kb);
      acc[m] = MFMA16(af, bfv, acc[m]);
    }
  }

  const int r0 = (lane >> 4) * 4;
  #pragma unroll
  for (int m = 0; m < MT; ++m) {
    #pragma unroll
    for (int q = 0; q < 4; ++q) {
      int row = m*16 + r0 + q;
      if (row < M && col < N)
        P[((size_t)ks*M + row)*N + col] = acc[m][q];
    }
  }
}

// ---------------- fused split-K sum + softmax over 512 logits -> bf16 probs into XH[.][1024:1536] ----------------
__global__ __launch_bounds__(256) void k_soft(const float* __restrict__ P, int KS, int M,
                                              unsigned short* __restrict__ dst)  // XH + s*1536 + 1024
{
  __shared__ float sm[512];
  __shared__ float red[8];
  const int m = blockIdx.x;
  const int tid = threadIdx.x, wv = tid>>6, ln = tid&63;
  for (int l = tid; l < 512; l += 256) {
    float s = 0.f;
    for (int ks = 0; ks < KS; ++ks) s += P[((size_t)ks*M + m)*512 + l];
    sm[l] = s;
  }
  __syncthreads();
  float mx = -1e30f;
  for (int l=tid; l<512; l+=256) mx = fmaxf(mx, sm[l]);
  #pragma unroll
  for (int o=32;o;o>>=1) mx = fmaxf(mx, __shfl_xor(mx,o,64));
  if (ln==0) red[wv]=mx;
  __syncthreads();
  mx = fmaxf(fmaxf(red[0],red[1]),fmaxf(red[2],red[3]));
  float se = 0.f;
  for (int l=tid; l<512; l+=256){ float ev=__expf(sm[l]-mx); sm[l]=ev; se+=ev; }
  __syncthreads();
  #pragma unroll
  for (int o=32;o;o>>=1) se += __shfl_xor(se,o,64);
  if (ln==0) red[wv]=se;
  __syncthreads();
  float invS = 1.f/(red[0]+red[1]+red[2]+red[3]);
  for (int l=tid; l<512; l+=256) dst[(size_t)m*1536 + l] = f2bf(sm[l]*invS);
}

// ---------------- et reduction: block per row; tanh; write Etb + scatter to children Xb ----------------
__global__ __launch_bounds__(256) void k_red4(const float* __restrict__ P, int KS, int M,
                                              const float* __restrict__ bias,
                                              unsigned short* __restrict__ Etb, int s,
                                              int snext, unsigned short* __restrict__ XbNext)
{
  const int row = blockIdx.x;
  const int col = threadIdx.x*4;
  float4 sum = *(const float4*)(bias + col);
  for (int ks = 0; ks < KS; ++ks) {
    float4 p = *(const float4*)(P + ((size_t)ks*M + row)*1024 + col);
    sum.x += p.x; sum.y += p.y; sum.z += p.z; sum.w += p.w;
  }
  u16x4 r;
  r[0]=f2bf(tanhfast(sum.x)); r[1]=f2bf(tanhfast(sum.y));
  r[2]=f2bf(tanhfast(sum.z)); r[3]=f2bf(tanhfast(sum.w));
  *(u16x4*)(Etb + (size_t)(s+row)*1024 + col) = r;
  if (XbNext) {
    int cbase = 4*(s+row) + 1;
    #pragma unroll
    for (int k=0;k<4;++k) {
      int cn = cbase + k;
      if (cn < 256) {
        int o = cn - snext;
        *(u16x4*)(XbNext + ((size_t)(o&3)*48 + (o>>2))*2560 + 512 + col) = r;
      }
    }
  }
}

// ---------------- LSTM epilogue: gates -> h,c; scatter h to children Xb (KS runtime) ----------------
__global__ __launch_bounds__(256) void k_epi(const float* __restrict__ P, int KS,
                                             const float* __restrict__ b_ih, const float* __restrict__ b_hh,
                                             float* __restrict__ Cb, unsigned short* __restrict__ XH,
                                             int s, int snext, unsigned short* __restrict__ XbNext){
  int i = s + blockIdx.x;
  int slot = (i - s) & 3, j = (i - s) >> 2;
  int p = (i - 1) >> 2;
  const float* bi = b_ih + (size_t)slot*4096;
  const float* bh = b_hh + (size_t)slot*4096;
  const int u = threadIdx.x*4;

  float4 ig, fg, gg, og;
  {
    float4 a, b;
    a = *(const float4*)(bi+u);      b = *(const float4*)(bh+u);      ig = make_float4(a.x+b.x,a.y+b.y,a.z+b.z,a.w+b.w);
    a = *(const float4*)(bi+1024+u); b = *(const float4*)(bh+1024+u); fg = make_float4(a.x+b.x,a.y+b.y,a.z+b.z,a.w+b.w);
    a = *(const float4*)(bi+2048+u); b = *(const float4*)(bh+2048+u); gg = make_float4(a.x+b.x,a.y+b.y,a.z+b.z,a.w+b.w);
    a = *(const float4*)(bi+3072+u); b = *(const float4*)(bh+3072+u); og = make_float4(a.x+b.x,a.y+b.y,a.z+b.z,a.w+b.w);
  }
  for (int ks = 0; ks < KS; ++ks) {
    const float* g = P + (((size_t)slot*KS + ks)*48 + j)*4096;
    float4 a;
    a = *(const float4*)(g+u);      ig.x+=a.x; ig.y+=a.y; ig.z+=a.z; ig.w+=a.w;
    a = *(const float4*)(g+1024+u); fg.x+=a.x; fg.y+=a.y; fg.z+=a.z; fg.w+=a.w;
    a = *(const float4*)(g+2048+u); gg.x+=a.x; gg.y+=a.y; gg.z+=a.z; gg.w+=a.w;
    a = *(const float4*)(g+3072+u); og.x+=a.x; og.y+=a.y; og.z+=a.z; og.w+=a.w;
  }
  float4 cp = *(const float4*)(Cb + (size_t)p*1024 + u);
  float4 cc, hh;
  cc.x = sigf(fg.x)*cp.x + sigf(ig.x)*tanhfast(gg.x); hh.x = sigf(og.x)*tanhfast(cc.x);
  cc.y = sigf(fg.y)*cp.y + sigf(ig.y)*tanhfast(gg.y); hh.y = sigf(og.y)*tanhfast(cc.y);
  cc.z = sigf(fg.z)*cp.z + sigf(ig.z)*tanhfast(gg.z); hh.z = sigf(og.z)*tanhfast(cc.z);
  cc.w = sigf(fg.w)*cp.w + sigf(ig.w)*tanhfast(gg.w); hh.w = sigf(og.w)*tanhfast(cc.w);
  *(float4*)(Cb + (size_t)i*1024 + u) = cc;
  u16x4 r; r[0]=f2bf(hh.x); r[1]=f2bf(hh.y); r[2]=f2bf(hh.z); r[3]=f2bf(hh.w);
  *(u16x4*)(XH + (size_t)i*1536 + u) = r;
  if (XbNext) {
    int cbase = 4*i + 1;
    #pragma unroll
    for (int k=0;k<4;++k) {
      int cn = cbase + k;
      if (cn < 256) {
        int o = cn - snext;
        *(u16x4*)(XbNext + ((size_t)(o&3)*48 + (o>>2))*2560 + 1536 + u) = r;
      }
    }
  }
}

// ---------------- loss per node (bf16 logits, register-cached single read) ----------------
__global__ __launch_bounds__(256) void k_loss(const unsigned short* __restrict__ Lgb,
                                              const int* __restrict__ values,
                                              float* __restrict__ Nl)
{
  __shared__ float red[8];
  const int node = blockIdx.x;
  const int tid = threadIdx.x, wv = tid>>6, ln = tid&63;
  const unsigned short* lg = Lgb + (size_t)node*NCLS;

  u16x8 v0 = *(const u16x8*)(lg + 0*2048 + tid*8);
  u16x8 v1 = *(const u16x8*)(lg + 1*2048 + tid*8);
  u16x8 v2 = *(const u16x8*)(lg + 2*2048 + tid*8);
  u16x8 v3 = *(const u16x8*)(lg + 3*2048 + tid*8);
  u16x8 v4;
  {
    int e = 8192 + tid*8;
    #pragma unroll
    for (int k=0;k<8;++k) v4[k] = (e+k < NCLS) ? lg[e+k] : (unsigned short)0xFF80;
  }

  float m = -1e30f;
  #pragma unroll
  for (int k=0;k<8;++k){
    m = fmaxf(m, bf2f(v0[k])); m = fmaxf(m, bf2f(v1[k]));
    m = fmaxf(m, bf2f(v2[k])); m = fmaxf(m, bf2f(v3[k]));
    m = fmaxf(m, bf2f(v4[k]));
  }
  #pragma unroll
  for (int o=32;o;o>>=1) m = fmaxf(m, __shfl_xor(m,o,64));
  if (ln==0) red[wv]=m;
  __syncthreads();
  m = fmaxf(fmaxf(red[0],red[1]),fmaxf(red[2],red[3]));
  __syncthreads();

  float s = 0.f;
  #pragma unroll
  for (int k=0;k<8;++k){
    s += __expf(bf2f(v0[k])-m); s += __expf(bf2f(v1[k])-m);
    s += __expf(bf2f(v2[k])-m); s += __expf(bf2f(v3[k])-m);
    s += __expf(bf2f(v4[k])-m);
  }
  #pragma unroll
  for (int o=32;o;o>>=1) s += __shfl_xor(s,o,64);
  if (ln==0) red[wv]=s;
  __syncthreads();
  s = red[0]+red[1]+red[2]+red[3];
  __syncthreads();
  float invs = 1.f/s;

  float q = 0.f;
  #pragma unroll
  for (int k=0;k<8;++k){
    q += __expf(__expf(bf2f(v0[k])-m)*invs);
    q += __expf(__expf(bf2f(v1[k])-m)*invs);
    q += __expf(__expf(bf2f(v2[k])-m)*invs);
    q += __expf(__expf(bf2f(v3[k])-m)*invs);
    if (8192 + tid*8 + k < NCLS) q += __expf(__expf(bf2f(v4[k])-m)*invs);
  }
  #pragma unroll
  for (int o=32;o;o>>=1) q += __shfl_xor(q,o,64);
  if (ln==0) red[wv]=q;
  __syncthreads();
  if (tid==0) {
    float qq = red[0]+red[1]+red[2]+red[3];
    int v = values[node];
    float pv = __expf(bf2f(lg[v])-m)*invs;
    float nl = __logf(qq) - pv;
    if (v == NCLS-1) nl *= 0.2f;
    Nl[node] = nl;
  }
}

__global__ __launch_bounds__(256) void k_final(const float* __restrict__ Nl, float* __restrict__ out){
  __shared__ float red[8];
  int tid = threadIdx.x, wv = tid>>6, ln = tid&63;
  float s = Nl[tid];
  #pragma unroll
  for (int o=32;o;o>>=1) s += __shfl_xor(s,o,64);
  if (ln==0) red[wv]=s;
  __syncthreads();
  if (tid==0) out[0] = red[0]+red[1]+red[2]+red[3];
}

static inline void gemm_skb(hipStream_t st, int MT, const unsigned short* A, int astride,
                            const unsigned short* B, int K, float* P, int N, int M)
{
  dim3 grid(N/64, K/128);
  #define SKCASE(MTv) k_gemm_skb<MTv><<<grid, 256, 0, st>>>(A,astride,B,K,P,N,M)
  switch(MT){
    case 1:  SKCASE(1);  break;
    case 4:  SKCASE(4);  break;
    case 11: SKCASE(11); break;
    default: SKCASE(16); break;
  }
  #undef SKCASE
}

extern "C" void kernel_launch(void* const* d_in, const int* in_sizes, int n_in,
                              void* d_out, int out_size, void* d_ws, size_t ws_size,
                              hipStream_t stream)
{
  const float* rootH = (const float*)d_in[0];
  const float* rootC = (const float*)d_in[1];
  const float* ann   = (const float*)d_in[2];
  const int*   values= (const int*)d_in[3];
  const float* emb   = (const float*)d_in[6];
  const float* W_ih  = (const float*)d_in[7];
  const float* W_hh  = (const float*)d_in[8];
  const float* b_ih  = (const float*)d_in[9];
  const float* b_hh  = (const float*)d_in[10];
  const float* W_att = (const float*)d_in[11];
  const float* b_att = (const float*)d_in[12];
  const float* W_pre = (const float*)d_in[13];
  const float* b_pre = (const float*)d_in[14];
  const float* W_out = (const float*)d_in[15];
  const float* b_out = (const float*)d_in[16];

  float* ws = (float*)d_ws;
  float* Cb  = ws; ws += 256*1024;              // fp32 c
  float* Nl  = ws; ws += 256;
  float* PB  = ws; ws += 4*10*48*4096;          // shared split-K partials (KS up to 10)
  unsigned short* Wbih  = (unsigned short*)ws;  // bf16 [4][4096][1536]
  unsigned short* Wbhh  = Wbih  + (size_t)4*4096*1536;   // bf16 [4][4096][1024]
  unsigned short* Wattb = Wbhh  + (size_t)4*4096*1024;   // bf16 [1024][1024]
  unsigned short* Bpre  = Wattb + 1024*1024;    // bf16 [1024][1536] = [W_pre_h | ANWT]
  unsigned short* Wpcb  = Bpre  + 1024*1536;    // bf16 [1024][1024] W_pre ctx half
  unsigned short* AHVb  = Wpcb  + 1024*1024;    // bf16 [512][1024]
  unsigned short* Annb  = AHVb  + 512*1024;     // bf16 [512][1024]
  unsigned short* XH    = Annb  + 512*1024;     // bf16 [256][1536] = [h | probs]
  unsigned short* Etb   = XH    + 256*1536;     // bf16 [256][1024]
  unsigned short* Xb    = Etb   + 256*1024;     // bf16 [4 levels][4][48][2560]
  unsigned short* Lgb   = Xb    + (size_t)4*4*48*2560;   // bf16 [256][10001] logits

  // ---- one-time prep ----
  k_cvtsmall<<<448, 256, 0, stream>>>(ann, W_att, W_pre, Annb, Wattb, Bpre, Wpcb);
  k_emb   <<<255,  64,  0, stream>>>(emb, values, Xb);
  // AHV = ann @ W_att^T + b_att  (bf16 out)
  k_gemm_fb<4><<<dim3(16,8), 256, 0, stream>>>(Annb, 1024, Wattb, 1024, b_att, AHVb, 1024, 0, 1024, 512);
  // ANWT[out][l] = W_pre_ctx[out]·ann[l] -> Bpre[out][1024:1536]
  k_gemm_fb<4><<<dim3(8,16), 256, 0, stream>>>(Wpcb, 1024, Annb, 1024, nullptr, Bpre, 1536, 1024, 512, 1024);
  k_root<<<1, 256, 0, stream>>>(rootH, rootC, Cb, XH, Xb);

  const int LS[6] = {0,1,5,21,85,256};
  for (int lev=0; lev<5; ++lev){
    int s=LS[lev], e=LS[lev+1], n=e-s;
    unsigned short* XbL = Xb + (size_t)(lev-1)*4*48*2560;       // this level's LSTM input (lev>=1)
    unsigned short* XbN = (lev<4) ? (Xb + (size_t)lev*4*48*2560) : nullptr;  // children's
    int snext = (lev<4) ? LS[lev+1] : 0;
    if (lev==1){
      // fused: convert W_ih/W_hh fp32 -> bf16 (NT read) while computing level-1 gates; KS=10
      k_lstm1c<<<dim3(64,10,4),256,0,stream>>>(XbL, W_ih, W_hh, Wbih, Wbhh, PB);
      k_epi<<<n,256,0,stream>>>(PB, 10, b_ih, b_hh, Cb, XH, s, snext, XbN);
    } else if (lev>1){
      if (lev==4)
        k_gemm_skzb2<3,16><<<dim3(64,5,4),256,0,stream>>>(XbL, 2560, Wbih, 1536, Wbhh, 1024, PB,
            4096, n, 48, 48*2560, 4096*1536, 4096*1024, 5);
      else
        k_gemm_skzb2<1,16><<<dim3(64,5,4),256,0,stream>>>(XbL, 2560, Wbih, 1536, Wbhh, 1024, PB,
            4096, n, 48, 48*2560, 4096*1536, 4096*1024, 5);
      k_epi<<<n,256,0,stream>>>(PB, 5, b_ih, b_hh, Cb, XH, s, snext, XbN);
    }
    int mtn = (n+15)/16;
    // attention logits [n x 512] = h · AHV^T (split-K MFMA) + fused softmax -> probs in XH
    gemm_skb(stream, mtn, XH + (size_t)s*1536, 1536, AHVb, 1024, PB, 512, n);
    k_soft<<<n,256,0,stream>>>(PB, 8, n, XH + (size_t)s*1536 + 1024);
    // et = tanh([h|probs] · Bpre^T + b_pre): split-K + per-row reduce (+ scatter to children Xb)
    gemm_skb(stream, mtn, XH + (size_t)s*1536, 1536, Bpre, 1536, PB, 1024, n);
    k_red4<<<n,256,0,stream>>>(PB, 12, n, b_pre, Etb, s, snext, XbN);
  }

  // W_out logits: fp32 B staged->LDS with convert (regular loads), bf16 output
  k_wout<<<626, 256, 0, stream>>>(Etb, W_out, b_out, Lgb);
  k_loss <<<256,256,0,stream>>>(Lgb, values, Nl);
  k_final<<<1,  256,0,stream>>>(Nl, (float*)d_out);
}